// Round 5
// baseline (1629.691 us; speedup 1.0000x reference)
//
#include <hip/hip_runtime.h>
#include <hip/hip_bf16.h>
#include <cstdint>

#define DMODEL 768
#define NB 64        // batch
#define NHEAD 12
#define DHEAD 64
#define SEQLEN 512
#define NDOM 3
#define NBLK 2
#define FFNH 3072
#define NBROWS (NDOM*NB)   // 192
#define NCH 8              // 64-row chunks per (n,b)
#define ROWCH 64

__device__ __forceinline__ float wsum64(float v){
  #pragma unroll
  for (int o = 32; o; o >>= 1) v += __shfl_xor(v, o, 64);
  return v;
}
__device__ __forceinline__ float dot4f(float4 a, float4 b){
  return fmaf(a.x, b.x, fmaf(a.y, b.y, fmaf(a.z, b.z, a.w * b.w)));
}
__device__ __forceinline__ uint32_t pk2(float lo, float hi){
  return (__float_as_uint(lo) >> 16) | (__float_as_uint(hi) & 0xFFFF0000u);
}
__device__ __forceinline__ float2 up2(uint32_t u){
  return make_float2(__uint_as_float(u << 16), __uint_as_float(u & 0xFFFF0000u));
}

// -------- LayerNorm: one wave per row of [rows, 768] --------
__global__ __launch_bounds__(256) void k_ln(const float* __restrict__ in,
    const float* __restrict__ w, const float* __restrict__ b,
    float* __restrict__ out, int rows){
  int gw = (blockIdx.x * 256 + threadIdx.x) >> 6;
  int lane = threadIdx.x & 63;
  if (gw >= rows) return;
  const float4* x4 = (const float4*)(in + (size_t)gw * DMODEL);
  float4 v0 = x4[lane], v1 = x4[64 + lane], v2 = x4[128 + lane];
  float s = v0.x+v0.y+v0.z+v0.w + v1.x+v1.y+v1.z+v1.w + v2.x+v2.y+v2.z+v2.w;
  float q = dot4f(v0,v0) + dot4f(v1,v1) + dot4f(v2,v2);
  s = wsum64(s); q = wsum64(q);
  float m = s * (1.0f / DMODEL);
  float var = q * (1.0f / DMODEL) - m * m;
  float r = rsqrtf(var + 1e-5f);
  const float4* w4 = (const float4*)w;
  const float4* b4 = (const float4*)b;
  float4* o4 = (float4*)(out + (size_t)gw * DMODEL);
  float4 vv[3] = {v0, v1, v2};
  #pragma unroll
  for (int seg = 0; seg < 3; ++seg){
    float4 ww = w4[seg*64 + lane], bb = b4[seg*64 + lane], x = vv[seg], o;
    o.x = (x.x - m) * r * ww.x + bb.x;
    o.y = (x.y - m) * r * ww.y + bb.y;
    o.z = (x.z - m) * r * ww.z + bb.z;
    o.w = (x.w - m) * r * ww.w + bb.w;
    o4[seg*64 + lane] = o;
  }
}

// -------- double LayerNorm (out_norm then cls_ln) --------
__global__ __launch_bounds__(256) void k_ln2(const float* __restrict__ in,
    const float* __restrict__ w1, const float* __restrict__ b1,
    const float* __restrict__ w2, const float* __restrict__ b2,
    float* __restrict__ out, int rows){
  int gw = (blockIdx.x * 256 + threadIdx.x) >> 6;
  int lane = threadIdx.x & 63;
  if (gw >= rows) return;
  const float4* x4 = (const float4*)(in + (size_t)gw * DMODEL);
  float4 vv[3] = {x4[lane], x4[64 + lane], x4[128 + lane]};
  float s = 0, q = 0;
  #pragma unroll
  for (int g = 0; g < 3; ++g){
    s += vv[g].x+vv[g].y+vv[g].z+vv[g].w;
    q += dot4f(vv[g], vv[g]);
  }
  s = wsum64(s); q = wsum64(q);
  float m = s * (1.0f/DMODEL);
  float r = rsqrtf(q * (1.0f/DMODEL) - m*m + 1e-5f);
  const float4* w14 = (const float4*)w1; const float4* b14 = (const float4*)b1;
  float4 yy[3];
  float s2 = 0, q2 = 0;
  #pragma unroll
  for (int g = 0; g < 3; ++g){
    float4 ww = w14[g*64 + lane], bb = b14[g*64 + lane], x = vv[g], o;
    o.x = (x.x - m)*r*ww.x + bb.x; o.y = (x.y - m)*r*ww.y + bb.y;
    o.z = (x.z - m)*r*ww.z + bb.z; o.w = (x.w - m)*r*ww.w + bb.w;
    yy[g] = o;
    s2 += o.x+o.y+o.z+o.w; q2 += dot4f(o,o);
  }
  s2 = wsum64(s2); q2 = wsum64(q2);
  float m2 = s2 * (1.0f/DMODEL);
  float r2 = rsqrtf(q2 * (1.0f/DMODEL) - m2*m2 + 1e-5f);
  const float4* w24 = (const float4*)w2; const float4* b24 = (const float4*)b2;
  float4* o4 = (float4*)(out + (size_t)gw * DMODEL);
  #pragma unroll
  for (int g = 0; g < 3; ++g){
    float4 ww = w24[g*64 + lane], bb = b24[g*64 + lane], y = yy[g], o;
    o.x = (y.x - m2)*r2*ww.x + bb.x; o.y = (y.y - m2)*r2*ww.y + bb.y;
    o.z = (y.z - m2)*r2*ww.z + bb.z; o.w = (y.w - m2)*r2*ww.w + bb.w;
    o4[g*64 + lane] = o;
  }
}

// -------- wave-per-4-columns GEMM: out[64,NC] = act(A[64,K] @ W[NC,K]^T + bias) --------
// bg = gw&7 so consecutive waves share weight rows (L2 locality).
template<int K, int NC, int ACT, bool RES>
__global__ __launch_bounds__(256) void k_gemmW(const float* __restrict__ A,
    const float* __restrict__ W, const float* __restrict__ bias,
    const float* __restrict__ res, float* __restrict__ out){
  int gw = (blockIdx.x * 256 + threadIdx.x) >> 6;   // 8*(NC/4) waves
  int lane = threadIdx.x & 63;
  int sl = lane & 7, g = lane >> 3;
  int bg = gw & 7; int j0 = (gw >> 3) * 4;
  const float4* a4 = (const float4*)(A + (size_t)(bg*8 + g) * K);
  const float4* w0 = (const float4*)(W + (size_t)(j0+0) * K);
  const float4* w1 = (const float4*)(W + (size_t)(j0+1) * K);
  const float4* w2 = (const float4*)(W + (size_t)(j0+2) * K);
  const float4* w3 = (const float4*)(W + (size_t)(j0+3) * K);
  float acc0 = 0, acc1 = 0, acc2 = 0, acc3 = 0;
  #pragma unroll 4
  for (int i = 0; i < K/32; ++i){
    float4 av = a4[i*8 + sl];
    acc0 += dot4f(av, w0[i*8 + sl]);
    acc1 += dot4f(av, w1[i*8 + sl]);
    acc2 += dot4f(av, w2[i*8 + sl]);
    acc3 += dot4f(av, w3[i*8 + sl]);
  }
  #pragma unroll
  for (int o = 1; o <= 4; o <<= 1){
    acc0 += __shfl_xor(acc0, o, 64);
    acc1 += __shfl_xor(acc1, o, 64);
    acc2 += __shfl_xor(acc2, o, 64);
    acc3 += __shfl_xor(acc3, o, 64);
  }
  if (sl == 0){
    int row = bg*8 + g;
    float4 bj = *(const float4*)(bias + j0);
    float a[4] = {acc0, acc1, acc2, acc3};
    float bb[4] = {bj.x, bj.y, bj.z, bj.w};
    float v[4];
    #pragma unroll
    for (int u = 0; u < 4; ++u){
      float t = (ACT == 2) ? a[u] * (1.0f/3.0f) + bb[u] : a[u] + bb[u];
      if (ACT == 1) t = t / (1.0f + __expf(-t));
      v[u] = t;
    }
    size_t o = (size_t)row * NC + j0;
    if (RES){
      float4 rr = *(const float4*)(res + o);
      v[0] += rr.x; v[1] += rr.y; v[2] += rr.z; v[3] += rr.w;
    }
    *(float4*)(out + o) = make_float4(v[0], v[1], v[2], v[3]);
  }
}

// -------- fused qproj + reductions: wave per (b,h) --------
__global__ __launch_bounds__(256) void k_qpr(const float* __restrict__ qh,
    const float* __restrict__ Wk, const float* __restrict__ snw,
    const float* __restrict__ snb, const float* __restrict__ bk,
    float* __restrict__ QW, float* __restrict__ SQW, float* __restrict__ SC){
  int w = (blockIdx.x * 256 + threadIdx.x) >> 6;   // 768 waves
  int lane = threadIdx.x & 63;
  int b = w / NHEAD, h = w - b * NHEAD;
  const float* qrow = qh + (size_t)b * DMODEL + h * DHEAD;
  const float* wbase = Wk + (size_t)h * DHEAD * DMODEL;
  float qp[12] = {};
  for (int e = 0; e < DHEAD; ++e){
    float qv = qrow[e];
    const float* wr = wbase + (size_t)e * DMODEL;
    #pragma unroll
    for (int k = 0; k < 12; ++k) qp[k] = fmaf(qv, wr[k*64 + lane], qp[k]);
  }
  float s1 = 0, s2 = 0;
  float* qwout = QW + (size_t)w * DMODEL;
  #pragma unroll
  for (int k = 0; k < 12; ++k){
    int d = k*64 + lane;
    float q = qp[k];
    float qwv = q * snw[d] * 0.125f;
    qwout[d] = qwv;
    s1 += qwv;
    s2 = fmaf(q, snb[d], s2);
  }
  float s3 = qrow[lane] * bk[h*DHEAD + lane];
  s1 = wsum64(s1); s2 = wsum64(s2); s3 = wsum64(s3);
  if (lane == 0){ SQW[w] = s1; SC[w] = 0.125f * (s2 + s3); }
}

// -------- fused attention v3: full-width 16-row LDS sub-tiles, bf16-packed x --------
// Block = (nb, ch): 64 rows as 4 sub-tiles of 16. Per sub-tile:
//  load(bf16-pack) -> phase1 (thread=(row,48-col slice), serial FMAs) -> shfl+LDS reduce
//  -> scores + online-softmax (defer-max across sub-tiles) -> phase2 PV from LDS into regs.
// Swizzle: oct (8 cols) phys = o ^ (row&7): conflict-free for all three access patterns.
__global__ __launch_bounds__(256) void k_attn3(const float* __restrict__ seq,
    const int* __restrict__ lens, const float* __restrict__ QW,
    const float* __restrict__ SQW, const float* __restrict__ SC,
    float* __restrict__ Pacc, float* __restrict__ Pden,
    float* __restrict__ Pc, float* __restrict__ Pmx){
  __shared__ uint32_t xu[16*384];        // 24 KB bf16-packed sub-tile
  __shared__ float qt[12*768];           // 36 KB fp32 QW for this b
  __shared__ float red[14*64];           // [v][wid*16+r] partial reduce
  __shared__ float er_s[16*12];          // [r][h]
  __shared__ float Mh_s[12], Dh_s[12], Ch_s[12], fs_s[12];
  int blk = blockIdx.x;
  int ch = blk & 7, nb = blk >> 3;
  int len = lens[nb];
  int row0 = ch * ROWCH;
  if (row0 >= len) return;
  int b = nb % NB;
  int tid = threadIdx.x;
  int lane = tid & 63, wid = tid >> 6;
  int nrows = len - row0; if (nrows > 64) nrows = 64;
  int nt = (nrows + 15) >> 4;
  int r1 = tid & 15, sl = tid >> 4;
  int hg3 = wid * 3;

  // stage qt once (coalesced, L2-hot)
  {
    const float4* src = (const float4*)(QW + (size_t)b * NHEAD * DMODEL);
    float4* dst = (float4*)qt;
    #pragma unroll
    for (int t = 0; t < 9; ++t) dst[tid + t*256] = src[tid + t*256];
  }
  if (tid < 12){ Mh_s[tid] = -3.0e38f; Dh_s[tid] = 0.0f; Ch_s[tid] = 0.0f; }

  float4 acc[3][3];
  #pragma unroll
  for (int j = 0; j < 3; ++j)
    #pragma unroll
    for (int t = 0; t < 3; ++t) acc[j][t] = make_float4(0,0,0,0);

  const float* rowbase = seq + ((size_t)nb * SEQLEN + row0) * DMODEL;

  for (int st = 0; st < nt; ++st){
    if (st) __syncthreads();             // prev phase2 done with xu/er_s
    // ---- load 16 rows, pack bf16, swizzled store ----
    #pragma unroll
    for (int t = 0; t < 6; ++t){
      int idx = tid + t*256;             // 0..1535
      int r = idx / 96, o = idx - r*96;
      const float4* g = (const float4*)(rowbase + (size_t)(st*16 + r) * DMODEL + o*8);
      float4 a = g[0], c = g[1];
      uint32_t u0 = pk2(a.x, a.y), u1 = pk2(a.z, a.w);
      uint32_t u2 = pk2(c.x, c.y), u3 = pk2(c.z, c.w);
      int po = o ^ (r & 7);
      *(uint4*)&xu[r*384 + po*4] = make_uint4(u0, u1, u2, u3);
    }
    __syncthreads();

    // ---- phase 1: thread (r1, sl) dots its 48 cols vs all 12 heads + stats ----
    float xr[48];
    #pragma unroll
    for (int j = 0; j < 6; ++j){
      int o = sl*6 + j;
      uint4 u = *(const uint4*)&xu[r1*384 + (o ^ (r1 & 7))*4];
      float2 p0 = up2(u.x), p1 = up2(u.y), p2 = up2(u.z), p3 = up2(u.w);
      xr[j*8+0] = p0.x; xr[j*8+1] = p0.y; xr[j*8+2] = p1.x; xr[j*8+3] = p1.y;
      xr[j*8+4] = p2.x; xr[j*8+5] = p2.y; xr[j*8+6] = p3.x; xr[j*8+7] = p3.y;
    }
    float smv = 0, qqv = 0;
    #pragma unroll
    for (int k = 0; k < 48; ++k){ smv += xr[k]; qqv = fmaf(xr[k], xr[k], qqv); }
    float dt[12];
    #pragma unroll
    for (int h = 0; h < 12; ++h){
      const float4* q4 = (const float4*)&qt[h*768 + sl*48];
      float s = 0;
      #pragma unroll
      for (int i = 0; i < 12; ++i){
        float4 q = q4[i];
        s = fmaf(q.x, xr[i*4+0], fmaf(q.y, xr[i*4+1], fmaf(q.z, xr[i*4+2], fmaf(q.w, xr[i*4+3], s))));
      }
      dt[h] = s;
    }
    // reduce over 4 slices within wave, then across 4 waves via red
    #pragma unroll
    for (int v = 0; v < 14; ++v){
      float val = (v < 12) ? dt[v] : (v == 12 ? smv : qqv);
      val += __shfl_xor(val, 16, 64);
      val += __shfl_xor(val, 32, 64);
      if (lane < 16) red[v*64 + wid*16 + r1] = val;
    }
    __syncthreads();

    // ---- scores + online softmax update (192 threads: (h, r)) ----
    if (tid < 192){
      int h = tid >> 4, r = tid & 15;
      float ds = red[h*64 + r] + red[h*64 + 16 + r] + red[h*64 + 32 + r] + red[h*64 + 48 + r];
      float smt = red[768 + r] + red[768 + 16 + r] + red[768 + 32 + r] + red[768 + 48 + r];
      float qqt = red[832 + r] + red[832 + 16 + r] + red[832 + 32 + r] + red[832 + 48 + r];
      float m = smt * (1.0f/DMODEL);
      float rs = rsqrtf(qqt * (1.0f/DMODEL) - m*m + 1e-5f);
      bool valid = (st*16 + r) < nrows;
      int bh = b*NHEAD + h;
      float sv = rs * (ds - m * SQW[bh]) + SC[bh];
      if (!valid) sv = -3.0e38f;
      float pmax = sv;
      pmax = fmaxf(pmax, __shfl_xor(pmax, 1, 64));
      pmax = fmaxf(pmax, __shfl_xor(pmax, 2, 64));
      pmax = fmaxf(pmax, __shfl_xor(pmax, 4, 64));
      pmax = fmaxf(pmax, __shfl_xor(pmax, 8, 64));
      float Mold = Mh_s[h];
      float Mnew = (pmax > Mold + 8.0f) ? pmax : Mold;   // defer-max (T13)
      float f = (Mnew > Mold) ? __expf(Mold - Mnew) : 1.0f;
      float e = valid ? __expf(sv - Mnew) : 0.0f;
      float er = e * rs;
      er_s[r*12 + h] = er;
      float den = e, cc = er * m;
      den += __shfl_xor(den, 1, 64); cc += __shfl_xor(cc, 1, 64);
      den += __shfl_xor(den, 2, 64); cc += __shfl_xor(cc, 2, 64);
      den += __shfl_xor(den, 4, 64); cc += __shfl_xor(cc, 4, 64);
      den += __shfl_xor(den, 8, 64); cc += __shfl_xor(cc, 8, 64);
      if (r == 0){
        Dh_s[h] = Dh_s[h] * f + den;
        Ch_s[h] = Ch_s[h] * f + cc;
        Mh_s[h] = Mnew;
        fs_s[h] = f;
      }
    }
    __syncthreads();

    // ---- phase 2: PV accumulate. thread = (hg: 3 heads, lane: 3 col-quads) ----
    float f0 = fs_s[hg3], f1 = fs_s[hg3+1], f2 = fs_s[hg3+2];
    #pragma unroll
    for (int t = 0; t < 3; ++t){
      acc[0][t].x *= f0; acc[0][t].y *= f0; acc[0][t].z *= f0; acc[0][t].w *= f0;
      acc[1][t].x *= f1; acc[1][t].y *= f1; acc[1][t].z *= f1; acc[1][t].w *= f1;
      acc[2][t].x *= f2; acc[2][t].y *= f2; acc[2][t].z *= f2; acc[2][t].w *= f2;
    }
    #pragma unroll
    for (int r = 0; r < 16; ++r){
      float e0 = er_s[r*12 + hg3], e1 = er_s[r*12 + hg3 + 1], e2 = er_s[r*12 + hg3 + 2];
      #pragma unroll
      for (int t = 0; t < 3; ++t){
        int q = t*64 + lane;
        int o = q >> 1;
        uint2 u = *(const uint2*)&xu[r*384 + (o ^ (r & 7))*4 + (q & 1)*2];
        float2 pa = up2(u.x), pb2 = up2(u.y);
        float4 xv = make_float4(pa.x, pa.y, pb2.x, pb2.y);
        acc[0][t].x = fmaf(e0, xv.x, acc[0][t].x); acc[0][t].y = fmaf(e0, xv.y, acc[0][t].y);
        acc[0][t].z = fmaf(e0, xv.z, acc[0][t].z); acc[0][t].w = fmaf(e0, xv.w, acc[0][t].w);
        acc[1][t].x = fmaf(e1, xv.x, acc[1][t].x); acc[1][t].y = fmaf(e1, xv.y, acc[1][t].y);
        acc[1][t].z = fmaf(e1, xv.z, acc[1][t].z); acc[1][t].w = fmaf(e1, xv.w, acc[1][t].w);
        acc[2][t].x = fmaf(e2, xv.x, acc[2][t].x); acc[2][t].y = fmaf(e2, xv.y, acc[2][t].y);
        acc[2][t].z = fmaf(e2, xv.z, acc[2][t].z); acc[2][t].w = fmaf(e2, xv.w, acc[2][t].w);
      }
    }
  }

  // ---- write partials ----
  size_t pb = (size_t)blk * NHEAD;
  if (tid < 12){ Pden[pb + tid] = Dh_s[tid]; Pc[pb + tid] = Ch_s[tid]; Pmx[pb + tid] = Mh_s[tid]; }
  float* pa = Pacc + pb * DMODEL;
  #pragma unroll
  for (int j = 0; j < 3; ++j)
    #pragma unroll
    for (int t = 0; t < 3; ++t)
      *(float4*)&pa[(size_t)(hg3 + j) * DMODEL + (t*64 + lane)*4] = acc[j][t];
}

// -------- combine active chunk partials over ch and domains + seq-LN affine --------
__global__ __launch_bounds__(256) void k_comb(const float* __restrict__ Pacc,
    const float* __restrict__ Pden, const float* __restrict__ Pc,
    const float* __restrict__ Pmx, const int* __restrict__ lens,
    const float* __restrict__ snw, const float* __restrict__ snb,
    float* __restrict__ wsum){
  int tid = blockIdx.x * 256 + threadIdx.x;   // NB*NHEAD*DMODEL
  int d = tid % DMODEL;
  int t = tid / DMODEL;
  int h = t % NHEAD;
  int b = t / NHEAD;
  float vec = 0.0f, csum = 0.0f;
  #pragma unroll
  for (int n = 0; n < NDOM; ++n){
    int nb = n*NB + b;
    int len = lens[nb];
    int na = (len + ROWCH - 1) >> 6; if (na > NCH) na = NCH;
    size_t p0 = (size_t)nb * NCH * NHEAD + h;
    float M = -3.0e38f;
    for (int c = 0; c < na; ++c) M = fmaxf(M, Pmx[p0 + (size_t)c*NHEAD]);
    float D = 0, V = 0, C = 0;
    for (int c = 0; c < na; ++c){
      size_t pi = p0 + (size_t)c*NHEAD;
      float w = __expf(Pmx[pi] - M);
      D = fmaf(w, Pden[pi], D);
      V = fmaf(w, Pacc[pi*DMODEL + d], V);
      C = fmaf(w, Pc[pi], C);
    }
    float inv = 1.0f / D;
    vec = fmaf(V, inv, vec);
    csum = fmaf(C, inv, csum);
  }
  wsum[tid] = (vec - csum) * snw[d] + 3.0f * snb[d];
}

// -------- ctxsum[b,he] = sum_d wsum[b,h,d]*Wv[he,d] + 3*bv[he], wave per 4 he --------
__global__ __launch_bounds__(256) void k_ctxv2(const float* __restrict__ wsum,
    const float* __restrict__ Wv, const float* __restrict__ bv, float* __restrict__ ctxsum){
  int gw = (blockIdx.x * 256 + threadIdx.x) >> 6;   // 8*192 waves
  int lane = threadIdx.x & 63;
  int sl = lane & 7, g = lane >> 3;
  int bg = gw & 7; int j0 = (gw >> 3) * 4;
  int h = j0 >> 6;
  const float4* a4 = (const float4*)(wsum + ((size_t)(bg*8 + g) * NHEAD + h) * DMODEL);
  const float4* w0 = (const float4*)(Wv + (size_t)(j0+0) * DMODEL);
  const float4* w1 = (const float4*)(Wv + (size_t)(j0+1) * DMODEL);
  const float4* w2 = (const float4*)(Wv + (size_t)(j0+2) * DMODEL);
  const float4* w3 = (const float4*)(Wv + (size_t)(j0+3) * DMODEL);
  float acc0 = 0, acc1 = 0, acc2 = 0, acc3 = 0;
  #pragma unroll 4
  for (int i = 0; i < DMODEL/32; ++i){
    float4 av = a4[i*8 + sl];
    acc0 += dot4f(av, w0[i*8 + sl]);
    acc1 += dot4f(av, w1[i*8 + sl]);
    acc2 += dot4f(av, w2[i*8 + sl]);
    acc3 += dot4f(av, w3[i*8 + sl]);
  }
  #pragma unroll
  for (int o = 1; o <= 4; o <<= 1){
    acc0 += __shfl_xor(acc0, o, 64);
    acc1 += __shfl_xor(acc1, o, 64);
    acc2 += __shfl_xor(acc2, o, 64);
    acc3 += __shfl_xor(acc3, o, 64);
  }
  if (sl == 0){
    float4 bb = *(const float4*)(bv + j0);
    float4 v = make_float4(acc0 + 3.0f*bb.x, acc1 + 3.0f*bb.y, acc2 + 3.0f*bb.z, acc3 + 3.0f*bb.w);
    *(float4*)(ctxsum + (size_t)(bg*8 + g) * DMODEL + j0) = v;
  }
}

// -------- gate + residual, wave per 4 cols --------
__global__ __launch_bounds__(256) void k_gate2(const float* __restrict__ ctx,
    const float* __restrict__ sctx, const float* __restrict__ Wg,
    const float* __restrict__ gb, float* __restrict__ out){
  int gw = (blockIdx.x * 256 + threadIdx.x) >> 6;   // 8*192 waves
  int lane = threadIdx.x & 63;
  int sl = lane & 7, g = lane >> 3;
  int bg = gw & 7; int j0 = (gw >> 3) * 4;
  int row = bg*8 + g;
  const float4* c4 = (const float4*)(ctx + (size_t)row * DMODEL);
  const float4* s4 = (const float4*)(sctx + (size_t)row * DMODEL);
  const float4* wr0 = (const float4*)(Wg + (size_t)(j0+0) * 2 * DMODEL);
  const float4* wr1 = (const float4*)(Wg + (size_t)(j0+1) * 2 * DMODEL);
  const float4* wr2 = (const float4*)(Wg + (size_t)(j0+2) * 2 * DMODEL);
  const float4* wr3 = (const float4*)(Wg + (size_t)(j0+3) * 2 * DMODEL);
  float acc0 = 0, acc1 = 0, acc2 = 0, acc3 = 0;
  #pragma unroll 4
  for (int i = 0; i < DMODEL/32; ++i){
    float4 cv = c4[i*8 + sl], sv = s4[i*8 + sl];
    acc0 += dot4f(cv, wr0[i*8 + sl]) + dot4f(sv, wr0[192 + i*8 + sl]);
    acc1 += dot4f(cv, wr1[i*8 + sl]) + dot4f(sv, wr1[192 + i*8 + sl]);
    acc2 += dot4f(cv, wr2[i*8 + sl]) + dot4f(sv, wr2[192 + i*8 + sl]);
    acc3 += dot4f(cv, wr3[i*8 + sl]) + dot4f(sv, wr3[192 + i*8 + sl]);
  }
  #pragma unroll
  for (int o = 1; o <= 4; o <<= 1){
    acc0 += __shfl_xor(acc0, o, 64);
    acc1 += __shfl_xor(acc1, o, 64);
    acc2 += __shfl_xor(acc2, o, 64);
    acc3 += __shfl_xor(acc3, o, 64);
  }
  if (sl == 0){
    size_t o = (size_t)row * DMODEL + j0;
    float4 bb = *(const float4*)(gb + j0);
    float4 cc = *(const float4*)(ctx + o);
    float4 ss = *(const float4*)(sctx + o);
    float4 v;
    v.x = cc.x + ss.x / (1.0f + __expf(-(acc0 + bb.x)));
    v.y = cc.y + ss.y / (1.0f + __expf(-(acc1 + bb.y)));
    v.z = cc.z + ss.z / (1.0f + __expf(-(acc2 + bb.z)));
    v.w = cc.w + ss.w / (1.0f + __expf(-(acc3 + bb.w)));
    *(float4*)(out + o) = v;
  }
}

// -------- classifier final dot --------
__global__ __launch_bounds__(256) void k_cls2(const float* __restrict__ h2,
    const float* __restrict__ w2, const float* __restrict__ b2, float* __restrict__ out){
  int b = blockIdx.x; int t = threadIdx.x;
  float acc = 0;
  for (int j = t; j < FFNH; j += 256) acc = fmaf(h2[(size_t)b*FFNH + j], w2[j], acc);
  acc = wsum64(acc);
  __shared__ float sh[4];
  if ((t & 63) == 0) sh[t >> 6] = acc;
  __syncthreads();
  if (t == 0) out[b] = sh[0] + sh[1] + sh[2] + sh[3] + b2[0];
}

extern "C" void kernel_launch(void* const* d_in, const int* in_sizes, int n_in,
                              void* d_out, int out_size, void* d_ws, size_t ws_size,
                              hipStream_t stream){
  const float* in_ctx = (const float*)d_in[0];
  const float* seq    = (const float*)d_in[1];
  const int*   lens   = (const int*)d_in[2];
  const float* qn_w   = (const float*)d_in[3];
  const float* qn_b   = (const float*)d_in[4];
  const float* sn_w   = (const float*)d_in[5];
  const float* sn_b   = (const float*)d_in[6];
  const float* in_w   = (const float*)d_in[7];
  const float* in_b   = (const float*)d_in[8];
  const float* out_w  = (const float*)d_in[9];
  const float* out_b  = (const float*)d_in[10];
  const float* gate_w = (const float*)d_in[11];
  const float* gate_b = (const float*)d_in[12];
  const float* fln_w  = (const float*)d_in[13];
  const float* fln_b  = (const float*)d_in[14];
  const float* fw1    = (const float*)d_in[15];
  const float* fb1    = (const float*)d_in[16];
  const float* fw2    = (const float*)d_in[17];
  const float* fb2    = (const float*)d_in[18];
  const float* on_w   = (const float*)d_in[19];
  const float* on_b   = (const float*)d_in[20];
  const float* cl_w   = (const float*)d_in[21];
  const float* cl_b   = (const float*)d_in[22];
  const float* cw1    = (const float*)d_in[23];
  const float* cb1    = (const float*)d_in[24];
  const float* cw2    = (const float*)d_in[25];
  const float* cb2    = (const float*)d_in[26];

  float* wsf = (float*)d_ws;
  size_t off = 0;
  auto alloc = [&](size_t n){ float* p = wsf + off; off += n; return p; };
  float* c0     = alloc((size_t)NB*DMODEL);
  float* c1     = alloc((size_t)NB*DMODEL);
  float* cmid   = alloc((size_t)NB*DMODEL);
  float* qln    = alloc((size_t)NB*DMODEL);
  float* qh     = alloc((size_t)NB*DMODEL);
  float* QW     = alloc((size_t)NB*NHEAD*DMODEL);
  float* SQWb   = alloc((size_t)NB*NHEAD);
  float* SCb    = alloc((size_t)NB*NHEAD);
  float* Pacc   = alloc((size_t)NBROWS*NCH*NHEAD*DMODEL);
  float* Pden   = alloc((size_t)NBROWS*NCH*NHEAD);
  float* Pc     = alloc((size_t)NBROWS*NCH*NHEAD);
  float* Pmx    = alloc((size_t)NBROWS*NCH*NHEAD);
  float* wsumb  = alloc((size_t)NB*NHEAD*DMODEL);
  float* ctxsum = alloc((size_t)NB*DMODEL);
  float* sctx   = alloc((size_t)NB*DMODEL);
  float* h0     = alloc((size_t)NB*DMODEL);
  float* h1     = alloc((size_t)NB*FFNH);
  (void)ws_size; (void)in_sizes; (void)n_in; (void)out_size;

  hipMemcpyAsync(c0, in_ctx, (size_t)NB*DMODEL*sizeof(float), hipMemcpyDeviceToDevice, stream);
  float* cur = c0; float* nxt = c1;

  for (int l = 0; l < NBLK; ++l){
    const float* Wq = in_w + (size_t)l * 3 * DMODEL * DMODEL;
    const float* Wk = Wq + (size_t)DMODEL * DMODEL;
    const float* Wv = Wq + (size_t)2 * DMODEL * DMODEL;
    const float* bq = in_b + (size_t)l * 3 * DMODEL;
    const float* bk = bq + DMODEL;
    const float* bv = bq + 2 * DMODEL;

    k_ln<<<16, 256, 0, stream>>>(cur, qn_w + l*DMODEL, qn_b + l*DMODEL, qln, NB);
    k_gemmW<DMODEL,DMODEL,0,false><<<384, 256, 0, stream>>>(qln, Wq, bq, nullptr, qh);
    k_qpr<<<192, 256, 0, stream>>>(qh, Wk, sn_w + l*DMODEL, sn_b + l*DMODEL, bk, QW, SQWb, SCb);
    k_attn3<<<NBROWS*NCH, 256, 0, stream>>>(seq, lens, QW, SQWb, SCb, Pacc, Pden, Pc, Pmx);
    k_comb<<<(NB*NHEAD*DMODEL)/256, 256, 0, stream>>>(Pacc, Pden, Pc, Pmx, lens, sn_w + l*DMODEL, sn_b + l*DMODEL, wsumb);
    k_ctxv2<<<384, 256, 0, stream>>>(wsumb, Wv, bv, ctxsum);
    k_gemmW<DMODEL,DMODEL,2,false><<<384, 256, 0, stream>>>(ctxsum, out_w + (size_t)l*DMODEL*DMODEL, out_b + l*DMODEL, nullptr, sctx);
    k_gate2<<<384, 256, 0, stream>>>(cur, sctx, gate_w + (size_t)l*DMODEL*2*DMODEL, gate_b + l*DMODEL, cmid);
    k_ln<<<16, 256, 0, stream>>>(cmid, fln_w + l*DMODEL, fln_b + l*DMODEL, h0, NB);
    k_gemmW<DMODEL,FFNH,1,false><<<1536, 256, 0, stream>>>(h0, fw1 + (size_t)l*FFNH*DMODEL, fb1 + l*FFNH, nullptr, h1);
    k_gemmW<FFNH,DMODEL,0,true><<<384, 256, 0, stream>>>(h1, fw2 + (size_t)l*DMODEL*FFNH, fb2 + l*DMODEL, cmid, nxt);
    float* t = cur; cur = nxt; nxt = t;
  }

  k_ln2<<<16, 256, 0, stream>>>(cur, on_w, on_b, cl_w, cl_b, h0, NB);
  k_gemmW<DMODEL,FFNH,1,false><<<1536, 256, 0, stream>>>(h0, cw1, cb1, nullptr, h1);
  k_cls2<<<64, 256, 0, stream>>>(h1, cw2, cb2, (float*)d_out);
}

// Round 6
// 661.373 us; speedup vs baseline: 2.4641x; 2.4641x over previous
//
#include <hip/hip_runtime.h>
#include <hip/hip_bf16.h>
#include <cstdint>

#define DMODEL 768
#define NB 64        // batch
#define NHEAD 12
#define DHEAD 64
#define SEQLEN 512
#define NDOM 3
#define NBLK 2
#define FFNH 3072
#define NBROWS (NDOM*NB)   // 192
#define NCH 16             // 32-row chunks per (n,b)
#define ROWCH 32

__device__ __forceinline__ float wsum64(float v){
  #pragma unroll
  for (int o = 32; o; o >>= 1) v += __shfl_xor(v, o, 64);
  return v;
}
__device__ __forceinline__ float wmax64(float v){
  #pragma unroll
  for (int o = 32; o; o >>= 1) v = fmaxf(v, __shfl_xor(v, o, 64));
  return v;
}
__device__ __forceinline__ float dot4f(float4 a, float4 b){
  return fmaf(a.x, b.x, fmaf(a.y, b.y, fmaf(a.z, b.z, a.w * b.w)));
}

// -------- LayerNorm: one wave per row of [rows, 768] --------
__global__ __launch_bounds__(256) void k_ln(const float* __restrict__ in,
    const float* __restrict__ w, const float* __restrict__ b,
    float* __restrict__ out, int rows){
  int gw = (blockIdx.x * 256 + threadIdx.x) >> 6;
  int lane = threadIdx.x & 63;
  if (gw >= rows) return;
  const float4* x4 = (const float4*)(in + (size_t)gw * DMODEL);
  float4 v0 = x4[lane], v1 = x4[64 + lane], v2 = x4[128 + lane];
  float s = v0.x+v0.y+v0.z+v0.w + v1.x+v1.y+v1.z+v1.w + v2.x+v2.y+v2.z+v2.w;
  float q = dot4f(v0,v0) + dot4f(v1,v1) + dot4f(v2,v2);
  s = wsum64(s); q = wsum64(q);
  float m = s * (1.0f / DMODEL);
  float var = q * (1.0f / DMODEL) - m * m;
  float r = rsqrtf(var + 1e-5f);
  const float4* w4 = (const float4*)w;
  const float4* b4 = (const float4*)b;
  float4* o4 = (float4*)(out + (size_t)gw * DMODEL);
  float4 vv[3] = {v0, v1, v2};
  #pragma unroll
  for (int seg = 0; seg < 3; ++seg){
    float4 ww = w4[seg*64 + lane], bb = b4[seg*64 + lane], x = vv[seg], o;
    o.x = (x.x - m) * r * ww.x + bb.x;
    o.y = (x.y - m) * r * ww.y + bb.y;
    o.z = (x.z - m) * r * ww.z + bb.z;
    o.w = (x.w - m) * r * ww.w + bb.w;
    o4[seg*64 + lane] = o;
  }
}

// -------- double LayerNorm (out_norm then cls_ln) --------
__global__ __launch_bounds__(256) void k_ln2(const float* __restrict__ in,
    const float* __restrict__ w1, const float* __restrict__ b1,
    const float* __restrict__ w2, const float* __restrict__ b2,
    float* __restrict__ out, int rows){
  int gw = (blockIdx.x * 256 + threadIdx.x) >> 6;
  int lane = threadIdx.x & 63;
  if (gw >= rows) return;
  const float4* x4 = (const float4*)(in + (size_t)gw * DMODEL);
  float4 vv[3] = {x4[lane], x4[64 + lane], x4[128 + lane]};
  float s = 0, q = 0;
  #pragma unroll
  for (int g = 0; g < 3; ++g){
    s += vv[g].x+vv[g].y+vv[g].z+vv[g].w;
    q += dot4f(vv[g], vv[g]);
  }
  s = wsum64(s); q = wsum64(q);
  float m = s * (1.0f/DMODEL);
  float r = rsqrtf(q * (1.0f/DMODEL) - m*m + 1e-5f);
  const float4* w14 = (const float4*)w1; const float4* b14 = (const float4*)b1;
  float4 yy[3];
  float s2 = 0, q2 = 0;
  #pragma unroll
  for (int g = 0; g < 3; ++g){
    float4 ww = w14[g*64 + lane], bb = b14[g*64 + lane], x = vv[g], o;
    o.x = (x.x - m)*r*ww.x + bb.x; o.y = (x.y - m)*r*ww.y + bb.y;
    o.z = (x.z - m)*r*ww.z + bb.z; o.w = (x.w - m)*r*ww.w + bb.w;
    yy[g] = o;
    s2 += o.x+o.y+o.z+o.w; q2 += dot4f(o,o);
  }
  s2 = wsum64(s2); q2 = wsum64(q2);
  float m2 = s2 * (1.0f/DMODEL);
  float r2 = rsqrtf(q2 * (1.0f/DMODEL) - m2*m2 + 1e-5f);
  const float4* w24 = (const float4*)w2; const float4* b24 = (const float4*)b2;
  float4* o4 = (float4*)(out + (size_t)gw * DMODEL);
  #pragma unroll
  for (int g = 0; g < 3; ++g){
    float4 ww = w24[g*64 + lane], bb = b24[g*64 + lane], y = yy[g], o;
    o.x = (y.x - m2)*r2*ww.x + bb.x; o.y = (y.y - m2)*r2*ww.y + bb.y;
    o.z = (y.z - m2)*r2*ww.z + bb.z; o.w = (y.w - m2)*r2*ww.w + bb.w;
    o4[g*64 + lane] = o;
  }
}

// -------- wave-per-4-columns GEMM: out[64,NC] = act(A[64,K] @ W[NC,K]^T + bias) --------
// bg = gw&7 so consecutive waves share weight rows (L2 locality).
template<int K, int NC, int ACT, bool RES>
__global__ __launch_bounds__(256) void k_gemmW(const float* __restrict__ A,
    const float* __restrict__ W, const float* __restrict__ bias,
    const float* __restrict__ res, float* __restrict__ out){
  int gw = (blockIdx.x * 256 + threadIdx.x) >> 6;   // 8*(NC/4) waves
  int lane = threadIdx.x & 63;
  int sl = lane & 7, g = lane >> 3;
  int bg = gw & 7; int j0 = (gw >> 3) * 4;
  const float4* a4 = (const float4*)(A + (size_t)(bg*8 + g) * K);
  const float4* w0 = (const float4*)(W + (size_t)(j0+0) * K);
  const float4* w1 = (const float4*)(W + (size_t)(j0+1) * K);
  const float4* w2 = (const float4*)(W + (size_t)(j0+2) * K);
  const float4* w3 = (const float4*)(W + (size_t)(j0+3) * K);
  float acc0 = 0, acc1 = 0, acc2 = 0, acc3 = 0;
  #pragma unroll 4
  for (int i = 0; i < K/32; ++i){
    float4 av = a4[i*8 + sl];
    acc0 += dot4f(av, w0[i*8 + sl]);
    acc1 += dot4f(av, w1[i*8 + sl]);
    acc2 += dot4f(av, w2[i*8 + sl]);
    acc3 += dot4f(av, w3[i*8 + sl]);
  }
  #pragma unroll
  for (int o = 1; o <= 4; o <<= 1){
    acc0 += __shfl_xor(acc0, o, 64);
    acc1 += __shfl_xor(acc1, o, 64);
    acc2 += __shfl_xor(acc2, o, 64);
    acc3 += __shfl_xor(acc3, o, 64);
  }
  if (sl == 0){
    int row = bg*8 + g;
    float4 bj = *(const float4*)(bias + j0);
    float a[4] = {acc0, acc1, acc2, acc3};
    float bb[4] = {bj.x, bj.y, bj.z, bj.w};
    float v[4];
    #pragma unroll
    for (int u = 0; u < 4; ++u){
      float t = (ACT == 2) ? a[u] * (1.0f/3.0f) + bb[u] : a[u] + bb[u];
      if (ACT == 1) t = t / (1.0f + __expf(-t));
      v[u] = t;
    }
    size_t o = (size_t)row * NC + j0;
    if (RES){
      float4 rr = *(const float4*)(res + o);
      v[0] += rr.x; v[1] += rr.y; v[2] += rr.z; v[3] += rr.w;
    }
    *(float4*)(out + o) = make_float4(v[0], v[1], v[2], v[3]);
  }
}

// -------- fused qproj + reductions: wave per (b,h) --------
__global__ __launch_bounds__(256) void k_qpr(const float* __restrict__ qh,
    const float* __restrict__ Wk, const float* __restrict__ snw,
    const float* __restrict__ snb, const float* __restrict__ bk,
    float* __restrict__ QW, float* __restrict__ SQW, float* __restrict__ SC){
  int w = (blockIdx.x * 256 + threadIdx.x) >> 6;   // 768 waves
  int lane = threadIdx.x & 63;
  int b = w / NHEAD, h = w - b * NHEAD;
  const float* qrow = qh + (size_t)b * DMODEL + h * DHEAD;
  const float* wbase = Wk + (size_t)h * DHEAD * DMODEL;
  float qp[12] = {};
  for (int e = 0; e < DHEAD; ++e){
    float qv = qrow[e];
    const float* wr = wbase + (size_t)e * DMODEL;
    #pragma unroll
    for (int k = 0; k < 12; ++k) qp[k] = fmaf(qv, wr[k*64 + lane], qp[k]);
  }
  float s1 = 0, s2 = 0;
  float* qwout = QW + (size_t)w * DMODEL;
  #pragma unroll
  for (int k = 0; k < 12; ++k){
    int d = k*64 + lane;
    float q = qp[k];
    float qwv = q * snw[d] * 0.125f;
    qwout[d] = qwv;
    s1 += qwv;
    s2 = fmaf(q, snb[d], s2);
  }
  float s3 = qrow[lane] * bk[h*DHEAD + lane];
  s1 = wsum64(s1); s2 = wsum64(s2); s3 = wsum64(s3);
  if (lane == 0){ SQW[w] = s1; SC[w] = 0.125f * (s2 + s3); }
}

// -------- fused attention v4: R3 streaming structure, 32-row chunks for TLP --------
// block = (nb, ch) chunk of 32 rows; 4 waves split 12 heads 3-each.
// Per row: LN stats + 3 head scores + online-softmax accumulate of raw row.
__global__ __launch_bounds__(256, 2) void k_attn4(const float* __restrict__ seq,
    const int* __restrict__ lens, const float* __restrict__ QW,
    const float* __restrict__ SQW, const float* __restrict__ SC,
    float* __restrict__ Pacc, float* __restrict__ Pden,
    float* __restrict__ Pc, float* __restrict__ Pmx){
  int blk = blockIdx.x;              // nb*NCH + ch
  int ch = blk & (NCH-1); int nb = blk >> 4;
  int wid = threadIdx.x >> 6; int lane = threadIdx.x & 63;
  int b = nb % NB;
  int len = lens[nb];
  int s0 = ch * ROWCH;
  if (s0 >= len) return;             // k_comb skips inactive chunks via lens
  int send = s0 + ROWCH < len ? s0 + ROWCH : len;
  int h0 = wid * 3;
  size_t pb = (size_t)blk * NHEAD + h0;
  const float4* qwb = (const float4*)(QW + ((size_t)b * NHEAD + h0) * DMODEL);
  float4 q0[3], q1[3], q2[3];
  #pragma unroll
  for (int j = 0; j < 3; ++j){
    q0[j] = qwb[j*(DMODEL/4) + lane];
    q1[j] = qwb[j*(DMODEL/4) + 64 + lane];
    q2[j] = qwb[j*(DMODEL/4) + 128 + lane];
  }
  float sqv[3], scv[3];
  #pragma unroll
  for (int j = 0; j < 3; ++j){ sqv[j] = SQW[b*NHEAD + h0 + j]; scv[j] = SC[b*NHEAD + h0 + j]; }
  float4 a0[3], a1[3], a2[3];
  #pragma unroll
  for (int j = 0; j < 3; ++j){
    a0[j] = make_float4(0,0,0,0); a1[j] = make_float4(0,0,0,0); a2[j] = make_float4(0,0,0,0);
  }
  float den[3] = {0,0,0}, cac[3] = {0,0,0}, mx[3] = {-3.0e38f,-3.0e38f,-3.0e38f};
  const float4* xr = (const float4*)(seq + ((size_t)nb * SEQLEN + s0) * DMODEL);
  float4 x0 = xr[lane], x1 = xr[64 + lane], x2 = xr[128 + lane];
  for (int s = s0; s < send; ++s){
    float4 c0 = x0, c1 = x1, c2 = x2;
    if (s + 1 < send){
      const float4* nx = (const float4*)(seq + ((size_t)nb * SEQLEN + s + 1) * DMODEL);
      x0 = nx[lane]; x1 = nx[64 + lane]; x2 = nx[128 + lane];
    }
    float sm = c0.x+c0.y+c0.z+c0.w + c1.x+c1.y+c1.z+c1.w + c2.x+c2.y+c2.z+c2.w;
    float qq = dot4f(c0,c0) + dot4f(c1,c1) + dot4f(c2,c2);
    float d0 = dot4f(q0[0],c0) + dot4f(q1[0],c1) + dot4f(q2[0],c2);
    float d1 = dot4f(q0[1],c0) + dot4f(q1[1],c1) + dot4f(q2[1],c2);
    float d2 = dot4f(q0[2],c0) + dot4f(q1[2],c1) + dot4f(q2[2],c2);
    sm = wsum64(sm); qq = wsum64(qq);
    d0 = wsum64(d0); d1 = wsum64(d1); d2 = wsum64(d2);
    float m = sm * (1.0f/DMODEL);
    float var = qq * (1.0f/DMODEL) - m * m;
    float r = rsqrtf(var + 1e-5f);
    float dt[3] = {d0, d1, d2};
    #pragma unroll
    for (int j = 0; j < 3; ++j){
      float score = r * (dt[j] - m * sqv[j]) + scv[j];
      if (score > mx[j] + 8.0f){           // defer-max rescale (rare)
        float f = __expf(mx[j] - score);
        den[j] *= f; cac[j] *= f;
        a0[j].x*=f; a0[j].y*=f; a0[j].z*=f; a0[j].w*=f;
        a1[j].x*=f; a1[j].y*=f; a1[j].z*=f; a1[j].w*=f;
        a2[j].x*=f; a2[j].y*=f; a2[j].z*=f; a2[j].w*=f;
        mx[j] = score;
      }
      float e = __expf(score - mx[j]);
      float er = e * r;
      a0[j].x = fmaf(er, c0.x, a0[j].x); a0[j].y = fmaf(er, c0.y, a0[j].y);
      a0[j].z = fmaf(er, c0.z, a0[j].z); a0[j].w = fmaf(er, c0.w, a0[j].w);
      a1[j].x = fmaf(er, c1.x, a1[j].x); a1[j].y = fmaf(er, c1.y, a1[j].y);
      a1[j].z = fmaf(er, c1.z, a1[j].z); a1[j].w = fmaf(er, c1.w, a1[j].w);
      a2[j].x = fmaf(er, c2.x, a2[j].x); a2[j].y = fmaf(er, c2.y, a2[j].y);
      a2[j].z = fmaf(er, c2.z, a2[j].z); a2[j].w = fmaf(er, c2.w, a2[j].w);
      den[j] += e;
      cac[j] = fmaf(er, m, cac[j]);
    }
  }
  #pragma unroll
  for (int j = 0; j < 3; ++j){
    float4* pa = (float4*)(Pacc + (pb + j) * DMODEL);
    pa[lane] = a0[j]; pa[64 + lane] = a1[j]; pa[128 + lane] = a2[j];
    if (lane == 0){ Pden[pb+j] = den[j]; Pc[pb+j] = cac[j]; Pmx[pb+j] = mx[j]; }
  }
}

// -------- combine active chunk partials over ch and domains + seq-LN affine --------
__global__ __launch_bounds__(256) void k_comb(const float* __restrict__ Pacc,
    const float* __restrict__ Pden, const float* __restrict__ Pc,
    const float* __restrict__ Pmx, const int* __restrict__ lens,
    const float* __restrict__ snw, const float* __restrict__ snb,
    float* __restrict__ wsum){
  int tid = blockIdx.x * 256 + threadIdx.x;   // NB*NHEAD*DMODEL
  int d = tid % DMODEL;
  int t = tid / DMODEL;
  int h = t % NHEAD;
  int b = t / NHEAD;
  float vec = 0.0f, csum = 0.0f;
  #pragma unroll
  for (int n = 0; n < NDOM; ++n){
    int nb = n*NB + b;
    int len = lens[nb];
    int na = (len + ROWCH - 1) >> 5; if (na > NCH) na = NCH;
    size_t p0 = (size_t)nb * NCH * NHEAD + h;
    float M = -3.0e38f;
    for (int c = 0; c < na; ++c) M = fmaxf(M, Pmx[p0 + (size_t)c*NHEAD]);
    float D = 0, V = 0, C = 0;
    for (int c = 0; c < na; ++c){
      size_t pi = p0 + (size_t)c*NHEAD;
      float w = __expf(Pmx[pi] - M);
      D = fmaf(w, Pden[pi], D);
      V = fmaf(w, Pacc[pi*DMODEL + d], V);
      C = fmaf(w, Pc[pi], C);
    }
    float inv = 1.0f / D;
    vec = fmaf(V, inv, vec);
    csum = fmaf(C, inv, csum);
  }
  wsum[tid] = (vec - csum) * snw[d] + 3.0f * snb[d];
}

// -------- ctxsum[b,he] = sum_d wsum[b,h,d]*Wv[he,d] + 3*bv[he], wave per 4 he --------
__global__ __launch_bounds__(256) void k_ctxv2(const float* __restrict__ wsum,
    const float* __restrict__ Wv, const float* __restrict__ bv, float* __restrict__ ctxsum){
  int gw = (blockIdx.x * 256 + threadIdx.x) >> 6;   // 8*192 waves
  int lane = threadIdx.x & 63;
  int sl = lane & 7, g = lane >> 3;
  int bg = gw & 7; int j0 = (gw >> 3) * 4;
  int h = j0 >> 6;
  const float4* a4 = (const float4*)(wsum + ((size_t)(bg*8 + g) * NHEAD + h) * DMODEL);
  const float4* w0 = (const float4*)(Wv + (size_t)(j0+0) * DMODEL);
  const float4* w1 = (const float4*)(Wv + (size_t)(j0+1) * DMODEL);
  const float4* w2 = (const float4*)(Wv + (size_t)(j0+2) * DMODEL);
  const float4* w3 = (const float4*)(Wv + (size_t)(j0+3) * DMODEL);
  float acc0 = 0, acc1 = 0, acc2 = 0, acc3 = 0;
  #pragma unroll 4
  for (int i = 0; i < DMODEL/32; ++i){
    float4 av = a4[i*8 + sl];
    acc0 += dot4f(av, w0[i*8 + sl]);
    acc1 += dot4f(av, w1[i*8 + sl]);
    acc2 += dot4f(av, w2[i*8 + sl]);
    acc3 += dot4f(av, w3[i*8 + sl]);
  }
  #pragma unroll
  for (int o = 1; o <= 4; o <<= 1){
    acc0 += __shfl_xor(acc0, o, 64);
    acc1 += __shfl_xor(acc1, o, 64);
    acc2 += __shfl_xor(acc2, o, 64);
    acc3 += __shfl_xor(acc3, o, 64);
  }
  if (sl == 0){
    float4 bb = *(const float4*)(bv + j0);
    float4 v = make_float4(acc0 + 3.0f*bb.x, acc1 + 3.0f*bb.y, acc2 + 3.0f*bb.z, acc3 + 3.0f*bb.w);
    *(float4*)(ctxsum + (size_t)(bg*8 + g) * DMODEL + j0) = v;
  }
}

// -------- gate + residual, wave per 4 cols --------
__global__ __launch_bounds__(256) void k_gate2(const float* __restrict__ ctx,
    const float* __restrict__ sctx, const float* __restrict__ Wg,
    const float* __restrict__ gb, float* __restrict__ out){
  int gw = (blockIdx.x * 256 + threadIdx.x) >> 6;   // 8*192 waves
  int lane = threadIdx.x & 63;
  int sl = lane & 7, g = lane >> 3;
  int bg = gw & 7; int j0 = (gw >> 3) * 4;
  int row = bg*8 + g;
  const float4* c4 = (const float4*)(ctx + (size_t)row * DMODEL);
  const float4* s4 = (const float4*)(sctx + (size_t)row * DMODEL);
  const float4* wr0 = (const float4*)(Wg + (size_t)(j0+0) * 2 * DMODEL);
  const float4* wr1 = (const float4*)(Wg + (size_t)(j0+1) * 2 * DMODEL);
  const float4* wr2 = (const float4*)(Wg + (size_t)(j0+2) * 2 * DMODEL);
  const float4* wr3 = (const float4*)(Wg + (size_t)(j0+3) * 2 * DMODEL);
  float acc0 = 0, acc1 = 0, acc2 = 0, acc3 = 0;
  #pragma unroll 4
  for (int i = 0; i < DMODEL/32; ++i){
    float4 cv = c4[i*8 + sl], sv = s4[i*8 + sl];
    acc0 += dot4f(cv, wr0[i*8 + sl]) + dot4f(sv, wr0[192 + i*8 + sl]);
    acc1 += dot4f(cv, wr1[i*8 + sl]) + dot4f(sv, wr1[192 + i*8 + sl]);
    acc2 += dot4f(cv, wr2[i*8 + sl]) + dot4f(sv, wr2[192 + i*8 + sl]);
    acc3 += dot4f(cv, wr3[i*8 + sl]) + dot4f(sv, wr3[192 + i*8 + sl]);
  }
  #pragma unroll
  for (int o = 1; o <= 4; o <<= 1){
    acc0 += __shfl_xor(acc0, o, 64);
    acc1 += __shfl_xor(acc1, o, 64);
    acc2 += __shfl_xor(acc2, o, 64);
    acc3 += __shfl_xor(acc3, o, 64);
  }
  if (sl == 0){
    size_t o = (size_t)row * DMODEL + j0;
    float4 bb = *(const float4*)(gb + j0);
    float4 cc = *(const float4*)(ctx + o);
    float4 ss = *(const float4*)(sctx + o);
    float4 v;
    v.x = cc.x + ss.x / (1.0f + __expf(-(acc0 + bb.x)));
    v.y = cc.y + ss.y / (1.0f + __expf(-(acc1 + bb.y)));
    v.z = cc.z + ss.z / (1.0f + __expf(-(acc2 + bb.z)));
    v.w = cc.w + ss.w / (1.0f + __expf(-(acc3 + bb.w)));
    *(float4*)(out + o) = v;
  }
}

// -------- classifier final dot --------
__global__ __launch_bounds__(256) void k_cls2(const float* __restrict__ h2,
    const float* __restrict__ w2, const float* __restrict__ b2, float* __restrict__ out){
  int b = blockIdx.x; int t = threadIdx.x;
  float acc = 0;
  for (int j = t; j < FFNH; j += 256) acc = fmaf(h2[(size_t)b*FFNH + j], w2[j], acc);
  acc = wsum64(acc);
  __shared__ float sh[4];
  if ((t & 63) == 0) sh[t >> 6] = acc;
  __syncthreads();
  if (t == 0) out[b] = sh[0] + sh[1] + sh[2] + sh[3] + b2[0];
}

extern "C" void kernel_launch(void* const* d_in, const int* in_sizes, int n_in,
                              void* d_out, int out_size, void* d_ws, size_t ws_size,
                              hipStream_t stream){
  const float* in_ctx = (const float*)d_in[0];
  const float* seq    = (const float*)d_in[1];
  const int*   lens   = (const int*)d_in[2];
  const float* qn_w   = (const float*)d_in[3];
  const float* qn_b   = (const float*)d_in[4];
  const float* sn_w   = (const float*)d_in[5];
  const float* sn_b   = (const float*)d_in[6];
  const float* in_w   = (const float*)d_in[7];
  const float* in_b   = (const float*)d_in[8];
  const float* out_w  = (const float*)d_in[9];
  const float* out_b  = (const float*)d_in[10];
  const float* gate_w = (const float*)d_in[11];
  const float* gate_b = (const float*)d_in[12];
  const float* fln_w  = (const float*)d_in[13];
  const float* fln_b  = (const float*)d_in[14];
  const float* fw1    = (const float*)d_in[15];
  const float* fb1    = (const float*)d_in[16];
  const float* fw2    = (const float*)d_in[17];
  const float* fb2    = (const float*)d_in[18];
  const float* on_w   = (const float*)d_in[19];
  const float* on_b   = (const float*)d_in[20];
  const float* cl_w   = (const float*)d_in[21];
  const float* cl_b   = (const float*)d_in[22];
  const float* cw1    = (const float*)d_in[23];
  const float* cb1    = (const float*)d_in[24];
  const float* cw2    = (const float*)d_in[25];
  const float* cb2    = (const float*)d_in[26];

  float* wsf = (float*)d_ws;
  size_t off = 0;
  auto alloc = [&](size_t n){ float* p = wsf + off; off += n; return p; };
  float* c0     = alloc((size_t)NB*DMODEL);
  float* c1     = alloc((size_t)NB*DMODEL);
  float* cmid   = alloc((size_t)NB*DMODEL);
  float* qln    = alloc((size_t)NB*DMODEL);
  float* qh     = alloc((size_t)NB*DMODEL);
  float* QW     = alloc((size_t)NB*NHEAD*DMODEL);
  float* SQWb   = alloc((size_t)NB*NHEAD);
  float* SCb    = alloc((size_t)NB*NHEAD);
  float* Pacc   = alloc((size_t)NBROWS*NCH*NHEAD*DMODEL);
  float* Pden   = alloc((size_t)NBROWS*NCH*NHEAD);
  float* Pc     = alloc((size_t)NBROWS*NCH*NHEAD);
  float* Pmx    = alloc((size_t)NBROWS*NCH*NHEAD);
  float* wsumb  = alloc((size_t)NB*NHEAD*DMODEL);
  float* ctxsum = alloc((size_t)NB*DMODEL);
  float* sctx   = alloc((size_t)NB*DMODEL);
  float* h0     = alloc((size_t)NB*DMODEL);
  float* h1     = alloc((size_t)NB*FFNH);
  (void)ws_size; (void)in_sizes; (void)n_in; (void)out_size;

  hipMemcpyAsync(c0, in_ctx, (size_t)NB*DMODEL*sizeof(float), hipMemcpyDeviceToDevice, stream);
  float* cur = c0; float* nxt = c1;

  for (int l = 0; l < NBLK; ++l){
    const float* Wq = in_w + (size_t)l * 3 * DMODEL * DMODEL;
    const float* Wk = Wq + (size_t)DMODEL * DMODEL;
    const float* Wv = Wq + (size_t)2 * DMODEL * DMODEL;
    const float* bq = in_b + (size_t)l * 3 * DMODEL;
    const float* bk = bq + DMODEL;
    const float* bv = bq + 2 * DMODEL;

    k_ln<<<16, 256, 0, stream>>>(cur, qn_w + l*DMODEL, qn_b + l*DMODEL, qln, NB);
    k_gemmW<DMODEL,DMODEL,0,false><<<384, 256, 0, stream>>>(qln, Wq, bq, nullptr, qh);
    k_qpr<<<192, 256, 0, stream>>>(qh, Wk, sn_w + l*DMODEL, sn_b + l*DMODEL, bk, QW, SQWb, SCb);
    k_attn4<<<NBROWS*NCH, 256, 0, stream>>>(seq, lens, QW, SQWb, SCb, Pacc, Pden, Pc, Pmx);
    k_comb<<<(NB*NHEAD*DMODEL)/256, 256, 0, stream>>>(Pacc, Pden, Pc, Pmx, lens, sn_w + l*DMODEL, sn_b + l*DMODEL, wsumb);
    k_ctxv2<<<384, 256, 0, stream>>>(wsumb, Wv, bv, ctxsum);
    k_gemmW<DMODEL,DMODEL,2,false><<<384, 256, 0, stream>>>(ctxsum, out_w + (size_t)l*DMODEL*DMODEL, out_b + l*DMODEL, nullptr, sctx);
    k_gate2<<<384, 256, 0, stream>>>(cur, sctx, gate_w + (size_t)l*DMODEL*2*DMODEL, gate_b + l*DMODEL, cmid);
    k_ln<<<16, 256, 0, stream>>>(cmid, fln_w + l*DMODEL, fln_b + l*DMODEL, h0, NB);
    k_gemmW<DMODEL,FFNH,1,false><<<1536, 256, 0, stream>>>(h0, fw1 + (size_t)l*FFNH*DMODEL, fb1 + l*FFNH, nullptr, h1);
    k_gemmW<FFNH,DMODEL,0,true><<<384, 256, 0, stream>>>(h1, fw2 + (size_t)l*DMODEL*FFNH, fb2 + l*DMODEL, cmid, nxt);
    float* t = cur; cur = nxt; nxt = t;
  }

  k_ln2<<<16, 256, 0, stream>>>(cur, on_w, on_b, cl_w, cl_b, h0, NB);
  k_gemmW<DMODEL,FFNH,1,false><<<1536, 256, 0, stream>>>(h0, cw1, cb1, nullptr, h1);
  k_cls2<<<64, 256, 0, stream>>>(h1, cw2, cb2, (float*)d_out);
}